// Round 1
// baseline (376.514 us; speedup 1.0000x reference)
//
#include <hip/hip_runtime.h>

#define S_TOTAL 262144
#define NNODES  24
#define INCH    32
#define HIDW    32

typedef _Float16 half2v __attribute__((ext_vector_type(2)));

// Packed f16 W1, layout [n][c2][w], pair = (c=2*c2, c=2*c2+1). 49 KB.
// Module-scope device global: avoids any dependence on ws_size.
__device__ unsigned g_pw1[NNODES * 16 * 32];

__device__ __forceinline__ unsigned pack2(float a, float b) {
  half2v h;
  h[0] = (_Float16)a;
  h[1] = (_Float16)b;
  return __builtin_bit_cast(unsigned, h);
}

__device__ __forceinline__ float dot2acc(unsigned a, unsigned b, float c) {
#if __has_builtin(__builtin_amdgcn_fdot2)
  return __builtin_amdgcn_fdot2(__builtin_bit_cast(half2v, a),
                                __builtin_bit_cast(half2v, b), c, false);
#else
  half2v x = __builtin_bit_cast(half2v, a), y = __builtin_bit_cast(half2v, b);
  return fmaf((float)x[0], (float)y[0], fmaf((float)x[1], (float)y[1], c));
#endif
}

__global__ void pack_w1_kernel(const float* __restrict__ W1) {
  int idx = blockIdx.x * 256 + threadIdx.x;
  if (idx >= NNODES * 16 * 32) return;
  int n = idx >> 9, r = idx & 511, c2 = r >> 5, w = r & 31;
  float a = W1[(n * INCH + 2 * c2    ) * HIDW + w];
  float b = W1[(n * INCH + 2 * c2 + 1) * HIDW + w];
  g_pw1[idx] = pack2(a, b);
}

__global__ __launch_bounds__(256) void mlp_kernel(
    const float* __restrict__ h, const int* __restrict__ valid,
    const float* __restrict__ b1, const float* __restrict__ W2,
    const float* __restrict__ b2, float* __restrict__ out) {
  int s = blockIdx.x * 256 + threadIdx.x;
  const float4* __restrict__ hrow =
      reinterpret_cast<const float4*>(h + (size_t)s * (NNODES * INCH));

  for (int n = 0; n < NNODES; ++n) {   // n is wave-uniform -> weights via SGPR
    int v = valid[s * NNODES + n];

    float4 hv[8];
#pragma unroll
    for (int i = 0; i < 8; ++i) hv[i] = make_float4(0.f, 0.f, 0.f, 0.f);
    if (v) {                           // exec-masked: invalid lanes skip HBM fetch
#pragma unroll
      for (int i = 0; i < 8; ++i) hv[i] = hrow[n * 8 + i];
    }

    unsigned hp[16];                   // relu(h) packed to half2
#pragma unroll
    for (int i = 0; i < 8; ++i) {
      hp[2 * i]     = pack2(fmaxf(hv[i].x, 0.f), fmaxf(hv[i].y, 0.f));
      hp[2 * i + 1] = pack2(fmaxf(hv[i].z, 0.f), fmaxf(hv[i].w, 0.f));
    }

    float hid[32];
#pragma unroll
    for (int w = 0; w < 32; ++w) hid[w] = b1[n * HIDW + w];

#pragma unroll
    for (int c2 = 0; c2 < 16; ++c2) {
#pragma unroll
      for (int w = 0; w < 32; ++w)
        hid[w] = dot2acc(hp[c2], g_pw1[(n * 16 + c2) * 32 + w], hid[w]);
    }

    float o0 = 0.f, o1 = 0.f, o2 = 0.f, o3 = 0.f;
#pragma unroll
    for (int w = 0; w < 32; w += 4) {
      o0 = fmaf(fmaxf(hid[w + 0], 0.f), W2[n * HIDW + w + 0], o0);
      o1 = fmaf(fmaxf(hid[w + 1], 0.f), W2[n * HIDW + w + 1], o1);
      o2 = fmaf(fmaxf(hid[w + 2], 0.f), W2[n * HIDW + w + 2], o2);
      o3 = fmaf(fmaxf(hid[w + 3], 0.f), W2[n * HIDW + w + 3], o3);
    }
    float res = (o0 + o1) + (o2 + o3) + b2[n];

    out[s * NNODES + n] = v ? res : 0.0f;
  }
}

extern "C" void kernel_launch(void* const* d_in, const int* in_sizes, int n_in,
                              void* d_out, int out_size, void* d_ws, size_t ws_size,
                              hipStream_t stream) {
  const float* h     = (const float*)d_in[0];
  const int*   valid = (const int*)d_in[1];
  const float* W1    = (const float*)d_in[2];
  const float* b1    = (const float*)d_in[3];
  const float* W2    = (const float*)d_in[4];
  const float* b2    = (const float*)d_in[5];
  float* out = (float*)d_out;

  hipLaunchKernelGGL(pack_w1_kernel, dim3((NNODES * 16 * 32 + 255) / 256),
                     dim3(256), 0, stream, W1);
  hipLaunchKernelGGL(mlp_kernel, dim3(S_TOTAL / 256), dim3(256), 0, stream,
                     h, valid, b1, W2, b2, out);
}

// Round 2
// 294.625 us; speedup vs baseline: 1.2779x; 1.2779x over previous
//
#include <hip/hip_runtime.h>

#define NS 262144
#define NN 24
#define CI 32
#define HW 32

typedef _Float16 half8 __attribute__((ext_vector_type(8)));
typedef float f32x4 __attribute__((ext_vector_type(4)));
typedef unsigned int u32x4 __attribute__((ext_vector_type(4)));

// Packed f16 B-fragments for W1: [n][half][lane][i], value =
// (f16) W1[n][k = (lane>>4)*8 + i][w = half*16 + (lane&15)]. 48 KB.
__device__ alignas(16) unsigned short g_w1f[NN * 2 * 64 * 8];

__global__ void pack_w1(const float* __restrict__ W1) {
  int idx = blockIdx.x * 256 + threadIdx.x;
  if (idx >= NN * 2 * 64 * 8) return;
  int i    = idx & 7;
  int lane = (idx >> 3) & 63;
  int hf   = (idx >> 9) & 1;
  int n    = idx >> 10;
  int k = (lane >> 4) * 8 + i;
  int w = hf * 16 + (lane & 15);
  _Float16 v = (_Float16)W1[(n * CI + k) * HW + w];
  g_w1f[idx] = __builtin_bit_cast(unsigned short, v);
}

__global__ __launch_bounds__(256) void mlp_mfma(
    const float* __restrict__ h, const int* __restrict__ valid,
    const float* __restrict__ b1, const float* __restrict__ W2,
    const float* __restrict__ b2, float* __restrict__ out) {
  const int tid  = threadIdx.x;
  const int lane = tid & 63;
  const int wv   = tid >> 6;      // wave 0..3
  const int r    = lane & 15;     // A: sample-row lane; B/C: hidden-col lane
  const int q    = lane >> 4;     // k-chunk group (A/B), row-group (C)
  const int sB   = blockIdx.x * 256;

  for (int n = 0; n < NN; ++n) {
    // Wave-uniform-per-n operands (L2-cached broadcast reads)
    half8 Bf0 = __builtin_bit_cast(half8,
        *(const u32x4*)&g_w1f[((n * 2 + 0) * 64 + lane) * 8]);
    half8 Bf1 = __builtin_bit_cast(half8,
        *(const u32x4*)&g_w1f[((n * 2 + 1) * 64 + lane) * 8]);
    float b1a = b1[n * HW + r];
    float b1b = b1[n * HW + 16 + r];
    float w2a = W2[n * HW + r];
    float w2b = W2[n * HW + 16 + r];
    float b2n = b2[n];

#pragma unroll
    for (int t = 0; t < 4; ++t) {
      const int s0   = sB + wv * 64 + t * 16;
      const int srow = s0 + r;

      // Per-row validity: the 4 lanes sharing (lane&15) share this row,
      // so exec-masking skips the whole 128B h line for invalid rows.
      const int vld = valid[srow * NN + n];
      f32x4 av0 = {0.f, 0.f, 0.f, 0.f}, av1 = {0.f, 0.f, 0.f, 0.f};
      if (vld) {
        const float* hp = &h[((size_t)srow * NN + n) * CI + q * 8];
        av0 = *(const f32x4*)hp;
        av1 = *(const f32x4*)(hp + 4);
      }

      half8 Af;
      Af[0] = (_Float16)fmaxf(av0[0], 0.f);
      Af[1] = (_Float16)fmaxf(av0[1], 0.f);
      Af[2] = (_Float16)fmaxf(av0[2], 0.f);
      Af[3] = (_Float16)fmaxf(av0[3], 0.f);
      Af[4] = (_Float16)fmaxf(av1[0], 0.f);
      Af[5] = (_Float16)fmaxf(av1[1], 0.f);
      Af[6] = (_Float16)fmaxf(av1[2], 0.f);
      Af[7] = (_Float16)fmaxf(av1[3], 0.f);

      // Layer 1: hid[16 samples][32 w] = relu(h)@W1 + b1 (C-init = bias)
      f32x4 c0 = {b1a, b1a, b1a, b1a};
      f32x4 c1 = {b1b, b1b, b1b, b1b};
      c0 = __builtin_amdgcn_mfma_f32_16x16x32_f16(Af, Bf0, c0, 0, 0, 0);
      c1 = __builtin_amdgcn_mfma_f32_16x16x32_f16(Af, Bf1, c1, 0, 0, 0);

      // Layer 2 partial: lane holds cols (r) and (16+r) of rows q*4+i
      float t0 = fmaxf(c0[0], 0.f) * w2a + fmaxf(c1[0], 0.f) * w2b;
      float t1 = fmaxf(c0[1], 0.f) * w2a + fmaxf(c1[1], 0.f) * w2b;
      float t2 = fmaxf(c0[2], 0.f) * w2a + fmaxf(c1[2], 0.f) * w2b;
      float t3 = fmaxf(c0[3], 0.f) * w2a + fmaxf(c1[3], 0.f) * w2b;

      // Butterfly sum over the 16 col-lanes (rows fixed within a group)
#pragma unroll
      for (int m = 1; m < 16; m <<= 1) {
        t0 += __shfl_xor(t0, m, 16);
        t1 += __shfl_xor(t1, m, 16);
        t2 += __shfl_xor(t2, m, 16);
        t3 += __shfl_xor(t3, m, 16);
      }

      if (r < 4) {
        const int m2   = q * 4 + r;
        const int srw  = s0 + m2;
        float val = r == 0 ? t0 : r == 1 ? t1 : r == 2 ? t2 : t3;
        const int vm  = valid[srw * NN + n];
        out[(size_t)srw * NN + n] = vm ? (val + b2n) : 0.0f;
      }
    }
  }
}

extern "C" void kernel_launch(void* const* d_in, const int* in_sizes, int n_in,
                              void* d_out, int out_size, void* d_ws, size_t ws_size,
                              hipStream_t stream) {
  const float* h     = (const float*)d_in[0];
  const int*   valid = (const int*)d_in[1];
  const float* W1    = (const float*)d_in[2];
  const float* b1    = (const float*)d_in[3];
  const float* W2    = (const float*)d_in[4];
  const float* b2    = (const float*)d_in[5];
  float* out = (float*)d_out;

  hipLaunchKernelGGL(pack_w1, dim3((NN * 2 * 64 * 8 + 255) / 256), dim3(256),
                     0, stream, W1);
  hipLaunchKernelGGL(mlp_mfma, dim3(NS / 256), dim3(256), 0, stream,
                     h, valid, b1, W2, b2, out);
}

// Round 3
// 231.019 us; speedup vs baseline: 1.6298x; 1.2753x over previous
//
#include <hip/hip_runtime.h>

#define NS 262144
#define NN 24
#define CI 32
#define HW 32

typedef _Float16 half8 __attribute__((ext_vector_type(8)));
typedef float f32x4 __attribute__((ext_vector_type(4)));
typedef unsigned int u32x4 __attribute__((ext_vector_type(4)));

// f16 fragments of W1^T used as the MFMA *A* operand:
// g_w1f[n][half][lane][i] = W1[n][c=(lane>>4)*8+i][w=half*16+(lane&15)]
// i.e. A[row=w][k=c] with row=lane&15, k=(lane>>4)*8+i.  48 KB.
__device__ alignas(16) unsigned short g_w1f[NN * 2 * 64 * 8];

__global__ void pack_w1(const float* __restrict__ W1) {
  int idx = blockIdx.x * 256 + threadIdx.x;
  if (idx >= NN * 2 * 64 * 8) return;
  int i    = idx & 7;
  int lane = (idx >> 3) & 63;
  int hf   = (idx >> 9) & 1;
  int n    = idx >> 10;
  int k = (lane >> 4) * 8 + i;        // contraction index c
  int w = hf * 16 + (lane & 15);      // hidden unit (C row)
  _Float16 v = (_Float16)W1[(n * CI + k) * HW + w];
  g_w1f[idx] = __builtin_bit_cast(unsigned short, v);
}

__global__ __launch_bounds__(256) void mlp_mfma(
    const float* __restrict__ h, const int* __restrict__ valid,
    const float* __restrict__ b1, const float* __restrict__ W2,
    const float* __restrict__ b2, float* __restrict__ out) {
  const int tid  = threadIdx.x;
  const int lane = tid & 63;
  const int wv   = tid >> 6;      // wave 0..3
  const int r    = lane & 15;     // B col = sample; A row = hidden w
  const int q    = lane >> 4;     // k-chunk group; C row-group
  const int sB   = blockIdx.x * 256;

  for (int n = 0; n < NN; ++n) {
    // W1^T fragments (A operand), wave-uniform per n — L1/L2 broadcast
    half8 Af0 = __builtin_bit_cast(half8,
        *(const u32x4*)&g_w1f[((n * 2 + 0) * 64 + lane) * 8]);
    half8 Af1 = __builtin_bit_cast(half8,
        *(const u32x4*)&g_w1f[((n * 2 + 1) * 64 + lane) * 8]);
    // Per-lane slices: reg i of c0 ↔ w=q*4+i, of c1 ↔ w=16+q*4+i
    f32x4 b1a = *(const f32x4*)&b1[n * HW + q * 4];
    f32x4 b1b = *(const f32x4*)&b1[n * HW + 16 + q * 4];
    f32x4 w2a = *(const f32x4*)&W2[n * HW + q * 4];
    f32x4 w2b = *(const f32x4*)&W2[n * HW + 16 + q * 4];
    float b2n = b2[n];

#pragma unroll
    for (int t = 0; t < 4; ++t) {
      const int s0   = sB + wv * 64 + t * 16;
      const int srow = s0 + r;

      // One valid read per (sample,n); the SAME lane later stores.
      const int vld = valid[srow * NN + n];
      f32x4 av0 = {0.f, 0.f, 0.f, 0.f}, av1 = {0.f, 0.f, 0.f, 0.f};
      if (vld) {                    // exec-masked: invalid rows skip the fetch
        const float* hp = &h[((size_t)srow * NN + n) * CI + q * 8];
        av0 = *(const f32x4*)hp;
        av1 = *(const f32x4*)(hp + 4);
      }

      // B operand: col=sample r, k=q*8+i  (relu(h)^T)
      half8 Hf;
      Hf[0] = (_Float16)fmaxf(av0[0], 0.f);
      Hf[1] = (_Float16)fmaxf(av0[1], 0.f);
      Hf[2] = (_Float16)fmaxf(av0[2], 0.f);
      Hf[3] = (_Float16)fmaxf(av0[3], 0.f);
      Hf[4] = (_Float16)fmaxf(av1[0], 0.f);
      Hf[5] = (_Float16)fmaxf(av1[1], 0.f);
      Hf[6] = (_Float16)fmaxf(av1[2], 0.f);
      Hf[7] = (_Float16)fmaxf(av1[3], 0.f);

      // C[w][sample] = W1^T @ relu(h)^T + b1 : reduction axis w is lane-local
      f32x4 c0 = {b1a[0], b1a[1], b1a[2], b1a[3]};
      f32x4 c1 = {b1b[0], b1b[1], b1b[2], b1b[3]};
      c0 = __builtin_amdgcn_mfma_f32_16x16x32_f16(Af0, Hf, c0, 0, 0, 0);
      c1 = __builtin_amdgcn_mfma_f32_16x16x32_f16(Af1, Hf, c1, 0, 0, 0);

      // Layer 2: 8 in-lane FMAs, then sum the 4 q-groups (2 shuffles)
      float p = 0.f;
#pragma unroll
      for (int i = 0; i < 4; ++i) {
        p = fmaf(fmaxf(c0[i], 0.f), w2a[i], p);
        p = fmaf(fmaxf(c1[i], 0.f), w2b[i], p);
      }
      p += __shfl_xor(p, 16);
      p += __shfl_xor(p, 32);

      if (lane < 16)                 // q==0 lanes: own sample srow, own vld
        out[(size_t)srow * NN + n] = vld ? (p + b2n) : 0.0f;
    }
  }
}

extern "C" void kernel_launch(void* const* d_in, const int* in_sizes, int n_in,
                              void* d_out, int out_size, void* d_ws, size_t ws_size,
                              hipStream_t stream) {
  const float* h     = (const float*)d_in[0];
  const int*   valid = (const int*)d_in[1];
  const float* W1    = (const float*)d_in[2];
  const float* b1    = (const float*)d_in[3];
  const float* W2    = (const float*)d_in[4];
  const float* b2    = (const float*)d_in[5];
  float* out = (float*)d_out;

  hipLaunchKernelGGL(pack_w1, dim3((NN * 2 * 64 * 8 + 255) / 256), dim3(256),
                     0, stream, W1);
  hipLaunchKernelGGL(mlp_mfma, dim3(NS / 256), dim3(256), 0, stream,
                     h, valid, b1, W2, b2, out);
}

// Round 5
// 229.047 us; speedup vs baseline: 1.6438x; 1.0086x over previous
//
#include <hip/hip_runtime.h>

#define NS 262144
#define NN 24
#define CI 32
#define HW 32

typedef _Float16 half2v __attribute__((ext_vector_type(2)));
typedef __fp16 fp16x2v __attribute__((ext_vector_type(2)));
typedef _Float16 half8 __attribute__((ext_vector_type(8)));
typedef float f32x4 __attribute__((ext_vector_type(4)));
typedef unsigned int u32x4 __attribute__((ext_vector_type(4)));

// f16 fragments of W1^T used as the MFMA *A* operand:
// g_w1f[n][half][lane][i] = W1[n][c=(lane>>4)*8+i][w=half*16+(lane&15)]
__device__ alignas(16) unsigned short g_w1f[NN * 2 * 64 * 8];

__global__ void pack_w1(const float* __restrict__ W1) {
  int idx = blockIdx.x * 256 + threadIdx.x;
  if (idx >= NN * 2 * 64 * 8) return;
  int i    = idx & 7;
  int lane = (idx >> 3) & 63;
  int hf   = (idx >> 9) & 1;
  int n    = idx >> 10;
  int k = (lane >> 4) * 8 + i;
  int w = hf * 16 + (lane & 15);
  _Float16 v = (_Float16)W1[(n * CI + k) * HW + w];
  g_w1f[idx] = __builtin_bit_cast(unsigned short, v);
}

__device__ __forceinline__ unsigned pkrtz(float a, float b) {
#if __has_builtin(__builtin_amdgcn_cvt_pkrtz)
  fp16x2v p = __builtin_amdgcn_cvt_pkrtz(a, b);
  return __builtin_bit_cast(unsigned, p);
#else
  half2v p;
  p[0] = (_Float16)a;
  p[1] = (_Float16)b;
  return __builtin_bit_cast(unsigned, p);
#endif
}

__global__ __launch_bounds__(256, 4) void mlp_mfma(
    const float* __restrict__ h, const int* __restrict__ valid,
    const float* __restrict__ b1, const float* __restrict__ W2,
    const float* __restrict__ b2, float* __restrict__ out) {
  const int tid  = threadIdx.x;
  const int lane = tid & 63;
  const int wv   = tid >> 6;
  const int r    = lane & 15;     // B col = sample; A row = hidden w
  const int q    = lane >> 4;     // k-chunk group; C row-group
  const int sB   = blockIdx.x * 256;

  int srow[4];
#pragma unroll
  for (int t = 0; t < 4; ++t) srow[t] = sB + wv * 64 + t * 16 + r;

  // --- valid prefetch stream, depth 2 (addresses independent of all data)
  int vcur[4], vnext[4], vfut[4];
#pragma unroll
  for (int t = 0; t < 4; ++t) {
    vcur[t]  = valid[srow[t] * NN + 0];
    vnext[t] = valid[srow[t] * NN + 1];
  }

  // --- h prefetch, depth 1, predicated on resident valid.
  // Zero-init ONCE; thereafter masked-out lanes keep stale values — safe,
  // since an invalid sample's garbage only affects its own C column, which
  // the store masks to 0.
  f32x4 raw0[4], raw1[4];
#pragma unroll
  for (int t = 0; t < 4; ++t) {
    raw0[t] = (f32x4){0.f, 0.f, 0.f, 0.f};
    raw1[t] = (f32x4){0.f, 0.f, 0.f, 0.f};
    if (vcur[t]) {
      const float* hp = &h[(size_t)(srow[t] * NN) * CI + q * 8];
      raw0[t] = *(const f32x4*)hp;
      raw1[t] = *(const f32x4*)(hp + 4);
    }
  }

  for (int n = 0; n < NN; ++n) {
    // Wave-uniform-per-n operands (L1-hot after first touch)
    half8 Af0 = __builtin_bit_cast(half8,
        *(const u32x4*)&g_w1f[((n * 2 + 0) * 64 + lane) * 8]);
    half8 Af1 = __builtin_bit_cast(half8,
        *(const u32x4*)&g_w1f[((n * 2 + 1) * 64 + lane) * 8]);
    f32x4 b1a = *(const f32x4*)&b1[n * HW + q * 4];
    f32x4 b1b = *(const f32x4*)&b1[n * HW + 16 + q * 4];
    f32x4 w2a = *(const f32x4*)&W2[n * HW + q * 4];
    f32x4 w2b = *(const f32x4*)&W2[n * HW + 16 + q * 4];
    float b2n = b2[n];

    // Pack LAST iteration's h loads (they had a full iteration to land)
    half8 Hf[4];
#pragma unroll
    for (int t = 0; t < 4; ++t) {
      unsigned u0 = pkrtz(fmaxf(raw0[t][0], 0.f), fmaxf(raw0[t][1], 0.f));
      unsigned u1 = pkrtz(fmaxf(raw0[t][2], 0.f), fmaxf(raw0[t][3], 0.f));
      unsigned u2 = pkrtz(fmaxf(raw1[t][0], 0.f), fmaxf(raw1[t][1], 0.f));
      unsigned u3 = pkrtz(fmaxf(raw1[t][2], 0.f), fmaxf(raw1[t][3], 0.f));
      u32x4 uu = {u0, u1, u2, u3};
      Hf[t] = __builtin_bit_cast(half8, uu);
    }

    // Issue NEXT valid (n+2) and NEXT h (n+1, predicated on resident vnext)
    const int nn1 = (n + 1 < NN) ? n + 1 : NN - 1;
    const int nn2 = (n + 2 < NN) ? n + 2 : NN - 1;
#pragma unroll
    for (int t = 0; t < 4; ++t) {
      vfut[t] = valid[srow[t] * NN + nn2];
      if (vnext[t]) {
        const float* hp = &h[(size_t)(srow[t] * NN + nn1) * CI + q * 8];
        raw0[t] = *(const f32x4*)hp;
        raw1[t] = *(const f32x4*)(hp + 4);
      }
    }

    // Compute + store for n (uses vcur for the output mask)
#pragma unroll
    for (int t = 0; t < 4; ++t) {
      f32x4 c0 = {b1a[0], b1a[1], b1a[2], b1a[3]};
      f32x4 c1 = {b1b[0], b1b[1], b1b[2], b1b[3]};
      c0 = __builtin_amdgcn_mfma_f32_16x16x32_f16(Af0, Hf[t], c0, 0, 0, 0);
      c1 = __builtin_amdgcn_mfma_f32_16x16x32_f16(Af1, Hf[t], c1, 0, 0, 0);

      float p = 0.f;
#pragma unroll
      for (int i = 0; i < 4; ++i) {
        p = fmaf(fmaxf(c0[i], 0.f), w2a[i], p);
        p = fmaf(fmaxf(c1[i], 0.f), w2b[i], p);
      }
      p += __shfl_xor(p, 16);
      p += __shfl_xor(p, 32);

      if (lane < 16)
        out[(size_t)srow[t] * NN + n] = vcur[t] ? (p + b2n) : 0.0f;
    }

    // Rotate prefetch streams
#pragma unroll
    for (int t = 0; t < 4; ++t) {
      vcur[t]  = vnext[t];
      vnext[t] = vfut[t];
    }
  }
}

extern "C" void kernel_launch(void* const* d_in, const int* in_sizes, int n_in,
                              void* d_out, int out_size, void* d_ws, size_t ws_size,
                              hipStream_t stream) {
  const float* h     = (const float*)d_in[0];
  const int*   valid = (const int*)d_in[1];
  const float* W1    = (const float*)d_in[2];
  const float* b1    = (const float*)d_in[3];
  const float* W2    = (const float*)d_in[4];
  const float* b2    = (const float*)d_in[5];
  float* out = (float*)d_out;

  hipLaunchKernelGGL(pack_w1, dim3((NN * 2 * 64 * 8 + 255) / 256), dim3(256),
                     0, stream, W1);
  hipLaunchKernelGGL(mlp_mfma, dim3(NS / 256), dim3(256), 0, stream,
                     h, valid, b1, W2, b2, out);
}